// Round 2
// baseline (577.173 us; speedup 1.0000x reference)
//
#include <hip/hip_runtime.h>
#include <math.h>

#define NROWS 131072
#define NSEG  64
#define HH    512
#define BM    256
#define BN    256
#define BK    32

typedef unsigned short u16;
typedef unsigned int   u32;
typedef __attribute__((ext_vector_type(8))) short short8;
typedef __attribute__((ext_vector_type(4))) float f32x4;
typedef __attribute__((ext_vector_type(4))) u32   u32x4;

__device__ __forceinline__ u32 f2u(float f){ union {float f; u32 u;} c; c.f=f; return c.u; }
__device__ __forceinline__ float u2f(u32 u){ union {u32 u; float f;} c; c.u=u; return c.f; }
__device__ __forceinline__ u16 bf16_rne(float f){
  u32 u = f2u(f);
  u32 r = u + 0x7FFFu + ((u >> 16) & 1u);
  return (u16)(r >> 16);
}
__device__ __forceinline__ float fast_tanh(float x){
  float e = __expf(2.0f * x);
  return 1.0f - __fdividef(2.0f, e + 1.0f);
}
// async 16B global->LDS; LDS dest is wave-uniform base + lane*16
__device__ __forceinline__ void gload_lds16(const void* g, void* l) {
  __builtin_amdgcn_global_load_lds((const __attribute__((address_space(1))) void*)g,
                                   (__attribute__((address_space(3))) void*)l, 16, 0, 0);
}

// ---------------- hproj[b][j] = sum_k hidden[b][k] * W[j][k]  (coalesced; 256 blocks)
__global__ __launch_bounds__(256)
void hproj_kernel(const float* __restrict__ hidden, const float* __restrict__ W,
                  float* __restrict__ hproj)
{
  const int b    = blockIdx.x >> 2;          // segment
  const int q    = blockIdx.x & 3;           // j-quarter
  const int tid  = threadIdx.x;
  const int wave = tid >> 6;
  const int lane = tid & 63;
  const float* hrow = hidden + (size_t)b * HH + lane * 8;
  const float4 h0 = *(const float4*)(hrow);
  const float4 h1 = *(const float4*)(hrow + 4);
  for (int j = q * 128 + wave; j < q * 128 + 128; j += 4) {
    const float* wrow = W + (size_t)j * 1024 + lane * 8;
    const float4 w0 = *(const float4*)(wrow);
    const float4 w1 = *(const float4*)(wrow + 4);
    float acc = h0.x*w0.x + h0.y*w0.y + h0.z*w0.z + h0.w*w0.w
              + h1.x*w1.x + h1.y*w1.y + h1.z*w1.z + h1.w*w1.w;
    #pragma unroll
    for (int o = 32; o; o >>= 1) acc += __shfl_xor(acc, o);
    if (lane == 0) hproj[(size_t)b * HH + j] = acc;
  }
}

// ---------------- split W2 = W[:, 512:1024] into bf16 hi/lo, row-major [j][k]
__global__ __launch_bounds__(256)
void w2split_kernel(const float* __restrict__ W, u16* __restrict__ hi, u16* __restrict__ lo)
{
  const int idx = blockIdx.x * 256 + threadIdx.x;   // j*512 + k
  const int j = idx >> 9, k = idx & 511;
  const float x = W[(size_t)j * 1024 + 512 + k];
  const u32 u = f2u(x);
  hi[idx] = (u16)(u >> 16);
  lo[idx] = bf16_rne(x - u2f(u & 0xFFFF0000u));
}

// ---------------- fused GEMM v2: 256x256 block tile, 512 thr / 8 waves (4Mx2N),
// wave tile 64x128, K-step 32, DOUBLE-BUFFERED LDS (128 KB), one barrier per
// K-step (T3/T4 minimum 2-phase: stage t+1 while computing t), XCD-bijective
// block swizzle (T1), full-XOR A chunk swizzle (all 8 chunks -> conflict-free
// ds_read_b128), setprio around MFMA cluster (T5).
// A staged fp32 via global_load_lds, split hi/lo in-register (v_perm);
// B pre-split bf16 hi/lo. 3-product split-bf16 MFMA, fused tanh+dot-v epilogue.
__global__ __launch_bounds__(512, 2)
void gemm_fused_kernel(const float* __restrict__ enc,
                       const u16* __restrict__ w2hi, const u16* __restrict__ w2lo,
                       const float* __restrict__ hproj, const float* __restrict__ vvec,
                       const int* __restrict__ seg, float* __restrict__ scores)
{
  __shared__ float sAf[2][BM * BK];   // 2 x 32 KB fp32 A tile
  __shared__ u16   sBh[2][BN * BK];   // 2 x 16 KB
  __shared__ u16   sBl[2][BN * BK];   // 2 x 16 KB

  const int tid  = threadIdx.x;
  const int b    = blockIdx.x;
  // nwg = 1024 (divisible by 8): bijective XCD swizzle; the (row0) pair sharing
  // an A panel lands on the same XCD, 8 dispatch-slots apart -> L2 hit.
  const int swz  = (b & 7) * 128 + (b >> 3);
  const int row0 = (swz >> 1) * BM;
  const int col0 = (swz & 1) * BN;

  const int wave = tid >> 6;
  const int lane = tid & 63;
  const int wrow = (wave >> 1) * 64;    // 4 row-waves
  const int wcol = (wave & 1) * 128;    // 2 col-waves
  const int l15  = lane & 15;
  const int quad = lane >> 4;

  // A staging: per issue 64 rows x 32 f32 (512 thr x 16 B). Thread t -> phys
  // chunk t&7 of row t>>3; source chunk XOR-swizzled with (row&7) so the
  // swizzled read below unswizzles (both-sides-or-neither).
  const int arow = tid >> 3;                        // 0..63
  const int acol = ((tid & 7) ^ (arow & 7)) * 4;
  const float* gA = enc + (size_t)(row0 + arow) * HH + acol;
  const int awb = wave * 256;                       // f32, wave-uniform base per issue

  // B staging: per issue 128 rows x 32 u16. phys chunk t&3 of row t>>2;
  // logical chunk (t&3)^((row>>1)&3)  (read side already conflict-free).
  const int brow = tid >> 2;                        // 0..127
  const int bcol = ((tid & 3) ^ ((brow >> 1) & 3)) * 8;
  const u16* gBh = w2hi + (size_t)(col0 + brow) * HH + bcol;
  const u16* gBl = w2lo + (size_t)(col0 + brow) * HH + bcol;
  const int bwb = wave * 512;                       // u16, wave-uniform base per issue

  f32x4 acc[4][8];
  #pragma unroll
  for (int i = 0; i < 4; i++)
    #pragma unroll
    for (int j = 0; j < 8; j++)
      acc[i][j] = (f32x4){0.f, 0.f, 0.f, 0.f};

  // ---- prologue: stage K-step 0 into buffer 0 ----
  #pragma unroll
  for (int i = 0; i < 4; i++) gload_lds16(gA + (size_t)i * 64 * HH, &sAf[0][i * 2048 + awb]);
  #pragma unroll
  for (int i = 0; i < 2; i++) gload_lds16(gBh + (size_t)i * 128 * HH, &sBh[0][i * 4096 + bwb]);
  #pragma unroll
  for (int i = 0; i < 2; i++) gload_lds16(gBl + (size_t)i * 128 * HH, &sBl[0][i * 4096 + bwb]);
  __syncthreads();   // vmcnt(0) drain + barrier: buf0 ready

  int bb = 0;
  for (int ks = 0; ks < HH; ks += BK) {
    // ---- phase 1: issue next K-step's stage into the other buffer ----
    const int kn = ks + BK;
    if (kn < HH) {
      #pragma unroll
      for (int i = 0; i < 4; i++)
        gload_lds16(gA + (size_t)i * 64 * HH + kn, &sAf[bb ^ 1][i * 2048 + awb]);
      #pragma unroll
      for (int i = 0; i < 2; i++)
        gload_lds16(gBh + (size_t)i * 128 * HH + kn, &sBh[bb ^ 1][i * 4096 + bwb]);
      #pragma unroll
      for (int i = 0; i < 2; i++)
        gload_lds16(gBl + (size_t)i * 128 * HH + kn, &sBl[bb ^ 1][i * 4096 + bwb]);
    }

    // ---- phase 2: A fragments from current buffer: read fp32, split hi/lo ----
    short8 ah[4], al[4];
    #pragma unroll
    for (int i = 0; i < 4; i++) {
      const int r  = wrow + i * 16 + l15;
      const int c0 = ((2 * quad)     ^ (r & 7)) * 4;   // logical chunk 2q
      const int c1 = ((2 * quad + 1) ^ (r & 7)) * 4;   // logical chunk 2q+1
      const f32x4 x0 = *(const f32x4*)&sAf[bb][r * BK + c0];
      const f32x4 x1 = *(const f32x4*)&sAf[bb][r * BK + c1];
      union { u32x4 w; short8 s; } H, L;
      #pragma unroll
      for (int p = 0; p < 4; p++) {
        const float xa = (p < 2) ? x0[2 * p] : x1[2 * p - 4];
        const float xb = (p < 2) ? x0[2 * p + 1] : x1[2 * p - 3];
        const u32 ua = f2u(xa), ub = f2u(xb);
        H.w[p] = __builtin_amdgcn_perm(ub, ua, 0x07060302u);   // [ub_hi16 | ua_hi16]
        const float ra = xa - u2f(ua & 0xFFFF0000u);
        const float rb = xb - u2f(ub & 0xFFFF0000u);
        L.w[p] = __builtin_amdgcn_perm(f2u(rb), f2u(ra), 0x07060302u);
      }
      ah[i] = H.s;
      al[i] = L.s;
    }

    // ---- phase 3: B streamed per col-frag; 12 MFMA per B pair ----
    __builtin_amdgcn_s_setprio(1);
    #pragma unroll
    for (int j = 0; j < 8; j++) {
      const int rr  = wcol + j * 16 + l15;
      const int off = rr * BK + (quad ^ ((rr >> 1) & 3)) * 8;
      const short8 bh = *(const short8*)&sBh[bb][off];
      const short8 bl = *(const short8*)&sBl[bb][off];
      #pragma unroll
      for (int i = 0; i < 4; i++) {
        acc[i][j] = __builtin_amdgcn_mfma_f32_16x16x32_bf16(ah[i], bh, acc[i][j], 0, 0, 0);
        acc[i][j] = __builtin_amdgcn_mfma_f32_16x16x32_bf16(al[i], bh, acc[i][j], 0, 0, 0);
        acc[i][j] = __builtin_amdgcn_mfma_f32_16x16x32_bf16(ah[i], bl, acc[i][j], 0, 0, 0);
      }
    }
    __builtin_amdgcn_s_setprio(0);

    // ---- one barrier per K-step: drains the stage issued ~768 MFMAs ago ----
    __syncthreads();
    bb ^= 1;
  }

  // ---- epilogue: + hproj, tanh, dot v, reduce over col-lanes, one atomic/row ----
  int   jn[8];
  float vv[8];
  #pragma unroll
  for (int j = 0; j < 8; j++) { jn[j] = col0 + wcol + j * 16 + l15; vv[j] = vvec[jn[j]]; }

  #pragma unroll
  for (int i = 0; i < 4; i++) {
    #pragma unroll
    for (int r = 0; r < 4; r++) {
      const int gn = row0 + wrow + i * 16 + quad * 4 + r;    // C/D: row=(lane>>4)*4+reg
      const float* hp = hproj + (size_t)seg[gn] * HH;
      float p = 0.f;
      #pragma unroll
      for (int j = 0; j < 8; j++) {
        const float c = acc[i][j][r] + hp[jn[j]];
        p += fast_tanh(c) * vv[j];
      }
      p += __shfl_xor(p, 1);
      p += __shfl_xor(p, 2);
      p += __shfl_xor(p, 4);
      p += __shfl_xor(p, 8);
      if (l15 == 0) atomicAdd(&scores[gn], p);
    }
  }
}

// ---------------- segment softmax: one block per segment (ids sorted)
__global__ __launch_bounds__(256)
void seg_softmax_kernel(const float* __restrict__ scores, const int* __restrict__ seg,
                        float* __restrict__ out)
{
  const int b    = blockIdx.x;
  const int tid  = threadIdx.x;
  const int wv   = tid >> 6;
  const int lane = tid & 63;
  __shared__ float red[4];

  int lo = 0, hi = NROWS;
  while (lo < hi) { int mid = (lo + hi) >> 1; if (seg[mid] < b) lo = mid + 1; else hi = mid; }
  const int start = lo;
  lo = 0; hi = NROWS;
  while (lo < hi) { int mid = (lo + hi) >> 1; if (seg[mid] < b + 1) lo = mid + 1; else hi = mid; }
  const int end = lo;

  float lm = -3.4e38f;
  for (int i = start + tid; i < end; i += 256) lm = fmaxf(lm, scores[i]);
  #pragma unroll
  for (int o = 32; o; o >>= 1) lm = fmaxf(lm, __shfl_xor(lm, o));
  if (lane == 0) red[wv] = lm;
  __syncthreads();
  const float gm = fmaxf(fmaxf(red[0], red[1]), fmaxf(red[2], red[3]));
  __syncthreads();

  float ls = 0.f;
  for (int i = start + tid; i < end; i += 256) ls += expf(scores[i] - gm);
  #pragma unroll
  for (int o = 32; o; o >>= 1) ls += __shfl_xor(ls, o);
  if (lane == 0) red[wv] = ls;
  __syncthreads();
  const float denom = red[0] + red[1] + red[2] + red[3];
  const float inv = 1.0f / denom;

  for (int i = start + tid; i < end; i += 256) out[i] = expf(scores[i] - gm) * inv;
}

extern "C" void kernel_launch(void* const* d_in, const int* in_sizes, int n_in,
                              void* d_out, int out_size, void* d_ws, size_t ws_size,
                              hipStream_t stream)
{
  const float* hidden = (const float*)d_in[0];
  const float* enc    = (const float*)d_in[1];
  const int*   seg    = (const int*)d_in[2];
  const float* W      = (const float*)d_in[3];
  const float* vvec   = (const float*)d_in[4];
  float* out = (float*)d_out;

  // ws layout: scores(512KB) | hproj(128KB) | w2hi(512KB) | w2lo(512KB)  ~1.7MB
  float* scores = (float*)d_ws;
  float* hproj  = scores + NROWS;
  u16*   w2hi   = (u16*)(hproj + NSEG * HH);
  u16*   w2lo   = w2hi + (size_t)HH * HH;

  hipMemsetAsync(scores, 0, NROWS * sizeof(float), stream);
  hproj_kernel<<<NSEG * 4, 256, 0, stream>>>(hidden, W, hproj);
  w2split_kernel<<<(HH * HH) / 256, 256, 0, stream>>>(W, w2hi, w2lo);
  gemm_fused_kernel<<<(NROWS / BM) * 2, 512, 0, stream>>>(enc, w2hi, w2lo,
                                                          hproj, vvec, seg, scores);
  seg_softmax_kernel<<<NSEG, 256, 0, stream>>>(scores, seg, out);
}

// Round 4
// 547.008 us; speedup vs baseline: 1.0551x; 1.0551x over previous
//
#include <hip/hip_runtime.h>
#include <math.h>

#define NROWS 131072
#define NSEG  64
#define HH    512
#define BM    256
#define BN    256
#define BK    32
#define NT    (HH / BK)   // 16 K-steps

typedef unsigned short u16;
typedef unsigned int   u32;
typedef __attribute__((ext_vector_type(8))) short short8;
typedef __attribute__((ext_vector_type(4))) float f32x4;
typedef __attribute__((ext_vector_type(4))) u32   u32x4;

__device__ __forceinline__ u32 f2u(float f){ union {float f; u32 u;} c; c.f=f; return c.u; }
__device__ __forceinline__ float u2f(u32 u){ union {u32 u; float f;} c; c.u=u; return c.f; }
__device__ __forceinline__ u16 bf16_rne(float f){
  u32 u = f2u(f);
  u32 r = u + 0x7FFFu + ((u >> 16) & 1u);
  return (u16)(r >> 16);
}
__device__ __forceinline__ float fast_tanh(float x){
  float e = __expf(2.0f * x);
  return 1.0f - __fdividef(2.0f, e + 1.0f);
}
// async 16B global->LDS; LDS dest is wave-uniform base + lane*16
__device__ __forceinline__ void gload_lds16(const void* g, void* l) {
  __builtin_amdgcn_global_load_lds((const __attribute__((address_space(1))) void*)g,
                                   (__attribute__((address_space(3))) void*)l, 16, 0, 0);
}

// ---------------- prep: fused w2split (blocks 0..1023) + hproj (blocks 1024..1279)
__global__ __launch_bounds__(256)
void prep_kernel(const float* __restrict__ hidden, const float* __restrict__ W,
                 float* __restrict__ hproj, u16* __restrict__ w2hi, u16* __restrict__ w2lo)
{
  const int bid = blockIdx.x;
  if (bid < 1024) {
    // split W2 = W[:, 512:1024] into bf16 hi/lo, row-major [j][k]
    const int idx = bid * 256 + threadIdx.x;   // j*512 + k
    const int j = idx >> 9, k = idx & 511;
    const float x = W[(size_t)j * 1024 + 512 + k];
    const u32 u = f2u(x);
    w2hi[idx] = (u16)(u >> 16);
    w2lo[idx] = bf16_rne(x - u2f(u & 0xFFFF0000u));
  } else {
    // hproj[b][j] = sum_k hidden[b][k] * W[j][k]
    const int b    = (bid - 1024) >> 2;        // segment
    const int q    = (bid - 1024) & 3;         // j-quarter
    const int tid  = threadIdx.x;
    const int wave = tid >> 6;
    const int lane = tid & 63;
    const float* hrow = hidden + (size_t)b * HH + lane * 8;
    const float4 h0 = *(const float4*)(hrow);
    const float4 h1 = *(const float4*)(hrow + 4);
    for (int j = q * 128 + wave; j < q * 128 + 128; j += 4) {
      const float* wrow = W + (size_t)j * 1024 + lane * 8;
      const float4 w0 = *(const float4*)(wrow);
      const float4 w1 = *(const float4*)(wrow + 4);
      float acc = h0.x*w0.x + h0.y*w0.y + h0.z*w0.z + h0.w*w0.w
                + h1.x*w1.x + h1.y*w1.y + h1.z*w1.z + h1.w*w1.w;
      #pragma unroll
      for (int o = 32; o; o >>= 1) acc += __shfl_xor(acc, o);
      if (lane == 0) hproj[(size_t)b * HH + j] = acc;
    }
  }
}

// ---------------- fused GEMM v4: 256x256 tile, 512 thr / 8 waves (4Mx2N),
// wave tile 64x128, K-step 32, depth-2 pipeline with COUNTED vmcnt (T4):
// raw s_barrier + s_waitcnt vmcnt(8) — only the tile consumed this iteration
// is waited on; the next tile's 8 loads stay in flight across the barrier
// (never drain to 0 in the main loop). XCD-bijective block swizzle (T1),
// full-XOR A chunk swizzle, setprio around MFMA cluster (T5).
// A staged fp32 via global_load_lds, split hi/lo in-register (v_perm);
// B pre-split bf16 hi/lo. 3-product split-bf16 MFMA, fused tanh+dot-v epilogue.
// Epilogue: per-wave partials -> LDS -> cross-wave (col-half) sum -> ONE
// coalesced store per row into this block's col-half buffer (fixes v3's
// two-writer race; no memset, no atomics).
__global__ __launch_bounds__(512, 2)
void gemm_fused_kernel(const float* __restrict__ enc,
                       const u16* __restrict__ w2hi, const u16* __restrict__ w2lo,
                       const float* __restrict__ hproj, const float* __restrict__ vvec,
                       const int* __restrict__ seg,
                       float* __restrict__ scores0, float* __restrict__ scores1)
{
  __shared__ float sAf[2][BM * BK];   // 2 x 32 KB fp32 A tile
  __shared__ u16   sBh[2][BN * BK];   // 2 x 16 KB
  __shared__ u16   sBl[2][BN * BK];   // 2 x 16 KB
  __shared__ float spart[8][64];      // 2 KB: per-wave per-row partials

  const int tid  = threadIdx.x;
  const int b    = blockIdx.x;
  // nwg = 1024 (divisible by 8): bijective XCD swizzle; the col-pair sharing
  // an A panel lands on the same XCD -> L2 hit on the second read.
  const int swz  = (b & 7) * 128 + (b >> 3);
  const int row0 = (swz >> 1) * BM;
  const int col0 = (swz & 1) * BN;

  const int wave = tid >> 6;
  const int lane = tid & 63;
  const int wrow = (wave >> 1) * 64;    // 4 row-waves
  const int wcol = (wave & 1) * 128;    // 2 col-waves
  const int l15  = lane & 15;
  const int quad = lane >> 4;

  // A staging: per issue 64 rows x 32 f32 (512 thr x 16 B). Thread t -> phys
  // chunk t&7 of row t>>3; source chunk XOR-swizzled with (row&7) so the
  // swizzled read below unswizzles (both-sides-or-neither).
  const int arow = tid >> 3;                        // 0..63
  const int acol = ((tid & 7) ^ (arow & 7)) * 4;
  const float* gA = enc + (size_t)(row0 + arow) * HH + acol;
  const int awb = wave * 256;                       // f32, wave-uniform base per issue

  // B staging: per issue 128 rows x 32 u16. phys chunk t&3 of row t>>2;
  // logical chunk (t&3)^((row>>1)&3)  (read side 2-way max per 16-lane group).
  const int brow = tid >> 2;                        // 0..127
  const int bcol = ((tid & 3) ^ ((brow >> 1) & 3)) * 8;
  const u16* gBh = w2hi + (size_t)(col0 + brow) * HH + bcol;
  const u16* gBl = w2lo + (size_t)(col0 + brow) * HH + bcol;
  const int bwb = wave * 512;                       // u16, wave-uniform base per issue

  f32x4 acc[4][8];
  #pragma unroll
  for (int i = 0; i < 4; i++)
    #pragma unroll
    for (int j = 0; j < 8; j++)
      acc[i][j] = (f32x4){0.f, 0.f, 0.f, 0.f};

  // 8 global_load_lds per wave per tile
  #define STAGE(dst, kk)                                                          \
  { _Pragma("unroll") for (int i = 0; i < 4; i++)                                 \
      gload_lds16(gA + (size_t)i * 64 * HH + (kk), &sAf[dst][i * 2048 + awb]);    \
    _Pragma("unroll") for (int i = 0; i < 2; i++)                                 \
      gload_lds16(gBh + (size_t)i * 128 * HH + (kk), &sBh[dst][i * 4096 + bwb]);  \
    _Pragma("unroll") for (int i = 0; i < 2; i++)                                 \
      gload_lds16(gBl + (size_t)i * 128 * HH + (kk), &sBl[dst][i * 4096 + bwb]); }

  // ---- prologue: stage tiles 0 and 1 (16 loads/wave in flight) ----
  STAGE(0, 0);
  STAGE(1, BK);

  int bb = 0;
  for (int t = 0; t < NT; ++t) {
    // wait for tile t's 8 loads only (oldest); tile t+1's 8 stay in flight
    if (t < NT - 1) { asm volatile("s_waitcnt vmcnt(8)" ::: "memory"); }
    else            { asm volatile("s_waitcnt vmcnt(0)" ::: "memory"); }
    __builtin_amdgcn_s_barrier();
    asm volatile("" ::: "memory");

    // ---- A fragments from buffer bb: read fp32, split hi/lo via v_perm ----
    short8 ah[4], al[4];
    #pragma unroll
    for (int i = 0; i < 4; i++) {
      const int r  = wrow + i * 16 + l15;
      const int c0 = ((2 * quad)     ^ (r & 7)) * 4;   // logical chunk 2q
      const int c1 = ((2 * quad + 1) ^ (r & 7)) * 4;   // logical chunk 2q+1
      const f32x4 x0 = *(const f32x4*)&sAf[bb][r * BK + c0];
      const f32x4 x1 = *(const f32x4*)&sAf[bb][r * BK + c1];
      union { u32x4 w; short8 s; } H, L;
      #pragma unroll
      for (int p = 0; p < 4; p++) {
        const float xa = (p < 2) ? x0[2 * p] : x1[2 * p - 4];
        const float xb = (p < 2) ? x0[2 * p + 1] : x1[2 * p - 3];
        const u32 ua = f2u(xa), ub = f2u(xb);
        H.w[p] = __builtin_amdgcn_perm(ub, ua, 0x07060302u);   // [ub_hi16 | ua_hi16]
        const float ra = xa - u2f(ua & 0xFFFF0000u);
        const float rb = xb - u2f(ub & 0xFFFF0000u);
        L.w[p] = __builtin_amdgcn_perm(f2u(rb), f2u(ra), 0x07060302u);
      }
      ah[i] = H.s;
      al[i] = L.s;
    }

    // ---- B streamed per col-frag; 12 MFMA per B pair ----
    __builtin_amdgcn_s_setprio(1);
    #pragma unroll
    for (int j = 0; j < 8; j++) {
      const int rr  = wcol + j * 16 + l15;
      const int off = rr * BK + (quad ^ ((rr >> 1) & 3)) * 8;
      const short8 bh = *(const short8*)&sBh[bb][off];
      const short8 bl = *(const short8*)&sBl[bb][off];
      #pragma unroll
      for (int i = 0; i < 4; i++) {
        acc[i][j] = __builtin_amdgcn_mfma_f32_16x16x32_bf16(ah[i], bh, acc[i][j], 0, 0, 0);
        acc[i][j] = __builtin_amdgcn_mfma_f32_16x16x32_bf16(al[i], bh, acc[i][j], 0, 0, 0);
        acc[i][j] = __builtin_amdgcn_mfma_f32_16x16x32_bf16(ah[i], bl, acc[i][j], 0, 0, 0);
      }
    }
    __builtin_amdgcn_s_setprio(0);

    // ---- all waves done reading buffer bb -> safe to overwrite with tile t+2
    asm volatile("" ::: "memory");
    __builtin_amdgcn_s_barrier();
    asm volatile("" ::: "memory");
    if (t < NT - 2) STAGE(bb, (t + 2) * BK);
    bb ^= 1;
  }
  #undef STAGE

  // ---- epilogue: + hproj, tanh, dot v, reduce over the wave's 128 cols,
  // deposit per-row partial in LDS, cross-wave sum of the two col-halves,
  // one coalesced store per row. ----
  int   jn[8];
  float vv[8];
  #pragma unroll
  for (int j = 0; j < 8; j++) { jn[j] = col0 + wcol + j * 16 + l15; vv[j] = vvec[jn[j]]; }

  #pragma unroll
  for (int i = 0; i < 4; i++) {
    #pragma unroll
    for (int r = 0; r < 4; r++) {
      const int lr = wrow + i * 16 + quad * 4 + r;           // local row 0..255
      const float* hp = hproj + (size_t)seg[row0 + lr] * HH;
      float p = 0.f;
      #pragma unroll
      for (int j = 0; j < 8; j++) {
        const float c = acc[i][j][r] + hp[jn[j]];
        p += fast_tanh(c) * vv[j];
      }
      p += __shfl_xor(p, 1);
      p += __shfl_xor(p, 2);
      p += __shfl_xor(p, 4);
      p += __shfl_xor(p, 8);
      if (l15 == 0) spart[wave][i * 16 + quad * 4 + r] = p;  // wave's 64-row slab
    }
  }
  __syncthreads();

  // waves 2k (cols 0..127) and 2k+1 (cols 128..255) cover the same rows:
  // sum the pair, one writer per row of this block's col-half buffer.
  float* __restrict__ sbuf = (col0 == 0) ? scores0 : scores1;
  if (tid < 256) {
    const int rw = tid >> 6;          // row-wave 0..3
    const int rr = tid & 63;
    sbuf[row0 + tid] = spart[rw * 2][rr] + spart[rw * 2 + 1][rr];
  }
}

// ---------------- segment softmax: one block per segment (ids sorted);
// scores = scores0 + scores1 (two col-half partials)
__global__ __launch_bounds__(256)
void seg_softmax_kernel(const float* __restrict__ scores0, const float* __restrict__ scores1,
                        const int* __restrict__ seg, float* __restrict__ out)
{
  const int b    = blockIdx.x;
  const int tid  = threadIdx.x;
  const int wv   = tid >> 6;
  const int lane = tid & 63;
  __shared__ float red[4];

  int lo = 0, hi = NROWS;
  while (lo < hi) { int mid = (lo + hi) >> 1; if (seg[mid] < b) lo = mid + 1; else hi = mid; }
  const int start = lo;
  lo = 0; hi = NROWS;
  while (lo < hi) { int mid = (lo + hi) >> 1; if (seg[mid] < b + 1) lo = mid + 1; else hi = mid; }
  const int end = lo;

  float lm = -3.4e38f;
  for (int i = start + tid; i < end; i += 256) lm = fmaxf(lm, scores0[i] + scores1[i]);
  #pragma unroll
  for (int o = 32; o; o >>= 1) lm = fmaxf(lm, __shfl_xor(lm, o));
  if (lane == 0) red[wv] = lm;
  __syncthreads();
  const float gm = fmaxf(fmaxf(red[0], red[1]), fmaxf(red[2], red[3]));
  __syncthreads();

  float ls = 0.f;
  for (int i = start + tid; i < end; i += 256) ls += expf(scores0[i] + scores1[i] - gm);
  #pragma unroll
  for (int o = 32; o; o >>= 1) ls += __shfl_xor(ls, o);
  if (lane == 0) red[wv] = ls;
  __syncthreads();
  const float denom = red[0] + red[1] + red[2] + red[3];
  const float inv = 1.0f / denom;

  for (int i = start + tid; i < end; i += 256)
    out[i] = expf(scores0[i] + scores1[i] - gm) * inv;
}

extern "C" void kernel_launch(void* const* d_in, const int* in_sizes, int n_in,
                              void* d_out, int out_size, void* d_ws, size_t ws_size,
                              hipStream_t stream)
{
  const float* hidden = (const float*)d_in[0];
  const float* enc    = (const float*)d_in[1];
  const int*   seg    = (const int*)d_in[2];
  const float* W      = (const float*)d_in[3];
  const float* vvec   = (const float*)d_in[4];
  float* out = (float*)d_out;

  // ws layout: scores0(512K) | scores1(512K) | hproj(128K) | w2hi(512K) | w2lo(512K)
  float* scores0 = (float*)d_ws;
  float* scores1 = scores0 + NROWS;
  float* hproj   = scores1 + NROWS;
  u16*   w2hi    = (u16*)(hproj + NSEG * HH);
  u16*   w2lo    = w2hi + (size_t)HH * HH;

  prep_kernel<<<1024 + NSEG * 4, 256, 0, stream>>>(hidden, W, hproj, w2hi, w2lo);
  gemm_fused_kernel<<<(NROWS / BM) * 2, 512, 0, stream>>>(enc, w2hi, w2lo,
                                                          hproj, vvec, seg,
                                                          scores0, scores1);
  seg_softmax_kernel<<<NSEG, 256, 0, stream>>>(scores0, scores1, seg, out);
}